// Round 1
// baseline (175.259 us; speedup 1.0000x reference)
//
#include <hip/hip_runtime.h>

using f32x4  = __attribute__((ext_vector_type(4))) float;
using bf16x8 = __attribute__((ext_vector_type(8))) __bf16;

// ---------- helpers ----------
__device__ __forceinline__ unsigned short f2bf(float f) {
  unsigned int u = __builtin_bit_cast(unsigned int, f);
  u = (u + 0x7FFFu + ((u >> 16) & 1u)) >> 16;   // RNE
  return (unsigned short)u;
}

__device__ __forceinline__ void g2lds16(const void* g, void* l) {
  __builtin_amdgcn_global_load_lds(
      (const __attribute__((address_space(1))) void*)g,
      (__attribute__((address_space(3))) void*)l, 16, 0, 0);
}

// ---------- f32 -> bf16 cast (8 elems/thread) ----------
__global__ __launch_bounds__(256) void k_cvt(const float* __restrict__ in,
                                             unsigned short* __restrict__ out, int n8) {
  int t = blockIdx.x * 256 + threadIdx.x;
  if (t >= n8) return;
  const float4* p = (const float4*)in;
  float4 a = p[2 * t], b = p[2 * t + 1];
  uint4 o;
  o.x = (unsigned)f2bf(a.x) | ((unsigned)f2bf(a.y) << 16);
  o.y = (unsigned)f2bf(a.z) | ((unsigned)f2bf(a.w) << 16);
  o.z = (unsigned)f2bf(b.x) | ((unsigned)f2bf(b.y) << 16);
  o.w = (unsigned)f2bf(b.z) | ((unsigned)f2bf(b.w) << 16);
  ((uint4*)out)[t] = o;
}

// ---------- A (E,D,R) -> Ab[j= e*16+r][d] bf16, K-major ----------
__global__ __launch_bounds__(256) void k_prep_ab(const float* __restrict__ A,
                                                 unsigned short* __restrict__ Ab) {
  int t = blockIdx.x * 256 + threadIdx.x;    // t = j*2048 + d
  int j = t >> 11, d = t & 2047;
  Ab[t] = f2bf(A[((size_t)(j >> 4) * 2048 + d) * 16 + (j & 15)]);
}

// ---------- Bexp (E,R,O) -> Bb[o][j= e*16+r] bf16, K-major ----------
__global__ __launch_bounds__(256) void k_prep_bb(const float* __restrict__ Bexp,
                                                 unsigned short* __restrict__ Bb) {
  int t = blockIdx.x * 256 + threadIdx.x;    // t = j*2048 + o (coalesced read)
  int j = t >> 11, o = t & 2047;
  Bb[(size_t)o * 128 + j] = f2bf(Bexp[(size_t)(j >> 4) * 32768 + (j & 15) * 2048 + o]);
}

// ---------- router: 1 wave per token, f32 precision ----------
__global__ __launch_bounds__(256) void k_router(const float* __restrict__ x,
                                                const float* __restrict__ Wr,
                                                float* __restrict__ wout) {
  int tok  = blockIdx.x * 4 + (threadIdx.x >> 6);
  int lane = threadIdx.x & 63;
  const float4* xr = (const float4*)(x + (size_t)tok * 2048);
  float4 xv[8];
#pragma unroll
  for (int c = 0; c < 8; c++) xv[c] = xr[c * 64 + lane];
  float lg[8];
#pragma unroll
  for (int e = 0; e < 8; e++) {
    const float4* wr = (const float4*)(Wr + e * 2048);
    float p = 0.f;
#pragma unroll
    for (int c = 0; c < 8; c++) {
      float4 wv = wr[c * 64 + lane];
      p += xv[c].x * wv.x + xv[c].y * wv.y + xv[c].z * wv.z + xv[c].w * wv.w;
    }
#pragma unroll
    for (int off = 32; off; off >>= 1) p += __shfl_xor(p, off);
    lg[e] = p;
  }
  int i1 = 0;
#pragma unroll
  for (int e = 1; e < 8; e++) if (lg[e] > lg[i1]) i1 = e;
  int i2 = (i1 == 0) ? 1 : 0;
#pragma unroll
  for (int e = 0; e < 8; e++) { if (e == i1) continue; if (lg[e] > lg[i2]) i2 = e; }
  float mx = lg[i1];
  float e2 = expf(lg[i2] - mx);
  float den = 1.f + e2;
  if (lane < 8) wout[(size_t)tok * 8 + lane] =
      (lane == i1) ? (1.f / den) : ((lane == i2) ? (e2 / den) : 0.f);
}

// ---------- LoRA-down GEMM: t[m][j] = f2bf( (xb . Ab^T)[m][j] * w[m][j>>4] ) ----------
__global__ __launch_bounds__(256) void k_gemm_lora(const unsigned short* __restrict__ xb,
                                                   const unsigned short* __restrict__ Ab,
                                                   const float* __restrict__ wrt,
                                                   unsigned short* __restrict__ tmat) {
  __shared__ unsigned short lsA[128 * 64];
  __shared__ unsigned short lsB[128 * 64];
  const int w = threadIdx.x >> 6, lane = threadIdx.x & 63;
  const int mBase = blockIdx.y * 128;
  const int wr = (w >> 1) * 64, wc = (w & 1) * 64;
  f32x4 z = {0.f, 0.f, 0.f, 0.f};
  f32x4 acc[4][4];
#pragma unroll
  for (int i = 0; i < 4; i++)
#pragma unroll
    for (int j = 0; j < 4; j++) acc[i][j] = z;

  for (int s = 0; s < 32; ++s) {
    int k0 = s * 64;
#pragma unroll
    for (int q = 0; q < 4; ++q) {
      int rowblk = w * 4 + q;
      int r  = rowblk * 8 + (lane >> 3);
      int cg = (lane & 7) ^ (r & 7);
      g2lds16(xb + (size_t)(mBase + r) * 2048 + k0 + cg * 8, (char*)lsA + rowblk * 1024);
      g2lds16(Ab + (size_t)r * 2048 + k0 + cg * 8,           (char*)lsB + rowblk * 1024);
    }
    __syncthreads();
#pragma unroll
    for (int kk = 0; kk < 2; ++kk) {
      bf16x8 af[4], bv[4];
#pragma unroll
      for (int i = 0; i < 4; ++i) {
        int r = wr + i * 16 + (lane & 15);
        int c = (kk * 4 + (lane >> 4)) ^ (r & 7);
        af[i] = *(const bf16x8*)((const char*)lsA + r * 128 + c * 16);
      }
#pragma unroll
      for (int j = 0; j < 4; ++j) {
        int r = wc + j * 16 + (lane & 15);
        int c = (kk * 4 + (lane >> 4)) ^ (r & 7);
        bv[j] = *(const bf16x8*)((const char*)lsB + r * 128 + c * 16);
      }
#pragma unroll
      for (int i = 0; i < 4; ++i)
#pragma unroll
        for (int j = 0; j < 4; ++j)
          acc[i][j] = __builtin_amdgcn_mfma_f32_16x16x32_bf16(af[i], bv[j], acc[i][j], 0, 0, 0);
    }
    __syncthreads();
  }
#pragma unroll
  for (int j = 0; j < 4; ++j) {
    int jj = wc + j * 16 + (lane & 15);
    int e  = jj >> 4;
#pragma unroll
    for (int i = 0; i < 4; ++i) {
      int m0 = mBase + wr + i * 16 + (lane >> 4) * 4;
#pragma unroll
      for (int q = 0; q < 4; ++q) {
        int m = m0 + q;
        tmat[(size_t)m * 128 + jj] = f2bf(acc[i][j][q] * wrt[(size_t)m * 8 + e]);
      }
    }
  }
}

// ---------- main GEMM: out = xb.Wb^T (K=2048) + tmat.Bb^T (K=128) + bias ----------
__global__ __launch_bounds__(256) void k_gemm_main(const unsigned short* __restrict__ xb,
                                                   const unsigned short* __restrict__ Wb,
                                                   const unsigned short* __restrict__ tmat,
                                                   const unsigned short* __restrict__ Bb,
                                                   const float* __restrict__ bias,
                                                   float* __restrict__ out) {
  __shared__ unsigned short lsA[128 * 64];
  __shared__ unsigned short lsB[128 * 64];
  const int w = threadIdx.x >> 6, lane = threadIdx.x & 63;
  const int mBase = blockIdx.y * 128;
  const int nBase = blockIdx.x * 128;
  const int wr = (w >> 1) * 64, wc = (w & 1) * 64;
  f32x4 z = {0.f, 0.f, 0.f, 0.f};
  f32x4 acc[4][4];
#pragma unroll
  for (int i = 0; i < 4; i++)
#pragma unroll
    for (int j = 0; j < 4; j++) acc[i][j] = z;

  for (int s = 0; s < 34; ++s) {
    const unsigned short* sA;
    const unsigned short* sB;
    int ldA, ldB, k0;
    if (s < 32) { sA = xb;   ldA = 2048; sB = Wb; ldB = 2048; k0 = s * 64; }
    else        { sA = tmat; ldA = 128;  sB = Bb; ldB = 128;  k0 = (s - 32) * 64; }
#pragma unroll
    for (int q = 0; q < 4; ++q) {
      int rowblk = w * 4 + q;
      int r  = rowblk * 8 + (lane >> 3);
      int cg = (lane & 7) ^ (r & 7);
      g2lds16(sA + (size_t)(mBase + r) * ldA + k0 + cg * 8, (char*)lsA + rowblk * 1024);
      g2lds16(sB + (size_t)(nBase + r) * ldB + k0 + cg * 8, (char*)lsB + rowblk * 1024);
    }
    __syncthreads();
#pragma unroll
    for (int kk = 0; kk < 2; ++kk) {
      bf16x8 af[4], bv[4];
#pragma unroll
      for (int i = 0; i < 4; ++i) {
        int r = wr + i * 16 + (lane & 15);
        int c = (kk * 4 + (lane >> 4)) ^ (r & 7);
        af[i] = *(const bf16x8*)((const char*)lsA + r * 128 + c * 16);
      }
#pragma unroll
      for (int j = 0; j < 4; ++j) {
        int r = wc + j * 16 + (lane & 15);
        int c = (kk * 4 + (lane >> 4)) ^ (r & 7);
        bv[j] = *(const bf16x8*)((const char*)lsB + r * 128 + c * 16);
      }
#pragma unroll
      for (int i = 0; i < 4; ++i)
#pragma unroll
        for (int j = 0; j < 4; ++j)
          acc[i][j] = __builtin_amdgcn_mfma_f32_16x16x32_bf16(af[i], bv[j], acc[i][j], 0, 0, 0);
    }
    __syncthreads();
  }
#pragma unroll
  for (int j = 0; j < 4; ++j) {
    int o = nBase + wc + j * 16 + (lane & 15);
    float bvs = bias[o];
#pragma unroll
    for (int i = 0; i < 4; ++i) {
      int m0 = mBase + wr + i * 16 + (lane >> 4) * 4;
#pragma unroll
      for (int q = 0; q < 4; ++q)
        out[(size_t)(m0 + q) * 2048 + o] = acc[i][j][q] + bvs;
    }
  }
}

extern "C" void kernel_launch(void* const* d_in, const int* in_sizes, int n_in,
                              void* d_out, int out_size, void* d_ws, size_t ws_size,
                              hipStream_t stream) {
  const float* x    = (const float*)d_in[0];   // (4,2048,2048)
  const float* W    = (const float*)d_in[1];   // (2048,2048)
  const float* bias = (const float*)d_in[2];   // (2048)
  const float* Wr   = (const float*)d_in[3];   // (8,2048)
  const float* A    = (const float*)d_in[4];   // (8,2048,16)
  const float* Bexp = (const float*)d_in[5];   // (8,16,2048)
  float* out = (float*)d_out;

  char* ws = (char*)d_ws;
  unsigned short* xb = (unsigned short*)(ws);                 // 33,554,432 B
  unsigned short* Wb = (unsigned short*)(ws + 33554432);      //  8,388,608 B
  unsigned short* Ab = (unsigned short*)(ws + 41943040);      //    524,288 B
  unsigned short* Bb = (unsigned short*)(ws + 42467328);      //    524,288 B
  unsigned short* tm = (unsigned short*)(ws + 42991616);      //  2,097,152 B
  float*          wr = (float*)(ws + 45088768);               //    262,144 B  (total ~43.3 MB)

  (void)in_sizes; (void)n_in; (void)out_size; (void)ws_size;

  k_cvt    <<<dim3(8192), 256, 0, stream>>>(x, xb, 16777216 / 8);
  k_cvt    <<<dim3(2048), 256, 0, stream>>>(W, Wb, 4194304 / 8);
  k_prep_ab<<<dim3(1024), 256, 0, stream>>>(A, Ab);
  k_prep_bb<<<dim3(1024), 256, 0, stream>>>(Bexp, Bb);
  k_router <<<dim3(2048), 256, 0, stream>>>(x, Wr, wr);
  k_gemm_lora<<<dim3(1, 64),  256, 0, stream>>>(xb, Ab, wr, tm);
  k_gemm_main<<<dim3(16, 64), 256, 0, stream>>>(xb, Wb, tm, Bb, bias, out);
}

// Round 2
// 143.242 us; speedup vs baseline: 1.2235x; 1.2235x over previous
//
#include <hip/hip_runtime.h>

using f32x4  = __attribute__((ext_vector_type(4))) float;
using bf16x8 = __attribute__((ext_vector_type(8))) __bf16;

// ---------- helpers ----------
__device__ __forceinline__ unsigned short f2bf(float f) {
  unsigned int u = __builtin_bit_cast(unsigned int, f);
  u = (u + 0x7FFFu + ((u >> 16) & 1u)) >> 16;   // RNE
  return (unsigned short)u;
}

__device__ __forceinline__ void g2lds16(const void* g, void* l) {
  __builtin_amdgcn_global_load_lds(
      (const __attribute__((address_space(1))) void*)g,
      (__attribute__((address_space(3))) void*)l, 16, 0, 0);
}

// ---------- combined weight prep: W cast + A repack + B repack ----------
__global__ __launch_bounds__(256) void k_prep(const float* __restrict__ W,
                                              const float* __restrict__ A,
                                              const float* __restrict__ Bexp,
                                              unsigned short* __restrict__ Wb,
                                              unsigned short* __restrict__ Ab,
                                              unsigned short* __restrict__ Bb) {
  int b = blockIdx.x;
  if (b < 2048) {                       // W: (2048,2048) f32 -> bf16, 8/thread
    int t = b * 256 + threadIdx.x;
    const float4* p = (const float4*)W;
    float4 a = p[2 * t], c = p[2 * t + 1];
    uint4 o;
    o.x = (unsigned)f2bf(a.x) | ((unsigned)f2bf(a.y) << 16);
    o.y = (unsigned)f2bf(a.z) | ((unsigned)f2bf(a.w) << 16);
    o.z = (unsigned)f2bf(c.x) | ((unsigned)f2bf(c.y) << 16);
    o.w = (unsigned)f2bf(c.z) | ((unsigned)f2bf(c.w) << 16);
    ((uint4*)Wb)[t] = o;
  } else if (b < 3072) {                // A (E,D,R) -> Ab[j=e*16+r][d]
    int t = (b - 2048) * 256 + threadIdx.x;
    int j = t >> 11, d = t & 2047;
    Ab[t] = f2bf(A[((size_t)(j >> 4) * 2048 + d) * 16 + (j & 15)]);
  } else {                              // Bexp (E,R,O) -> Bb[o][j=e*16+r]
    int t = (b - 3072) * 256 + threadIdx.x;
    int j = t >> 11, o = t & 2047;
    Bb[(size_t)o * 128 + j] = f2bf(Bexp[(size_t)(j >> 4) * 32768 + (j & 15) * 2048 + o]);
  }
}

// ---------- router (f32 exact) fused with x -> bf16 cast ----------
__global__ __launch_bounds__(256) void k_router_cast(const float* __restrict__ x,
                                                     const float* __restrict__ Wr,
                                                     unsigned short* __restrict__ xb,
                                                     float* __restrict__ wout) {
  int tok  = blockIdx.x * 4 + (threadIdx.x >> 6);
  int lane = threadIdx.x & 63;
  const float4* xr = (const float4*)(x + (size_t)tok * 2048);
  float4 xv[8];
#pragma unroll
  for (int c = 0; c < 8; c++) xv[c] = xr[c * 64 + lane];
  // cast + store this row as bf16 (8 B/lane, coalesced)
  uint2* xbr = (uint2*)(xb + (size_t)tok * 2048);
#pragma unroll
  for (int c = 0; c < 8; c++) {
    uint2 o;
    o.x = (unsigned)f2bf(xv[c].x) | ((unsigned)f2bf(xv[c].y) << 16);
    o.y = (unsigned)f2bf(xv[c].z) | ((unsigned)f2bf(xv[c].w) << 16);
    xbr[c * 64 + lane] = o;
  }
  float lg[8];
#pragma unroll
  for (int e = 0; e < 8; e++) {
    const float4* wr = (const float4*)(Wr + e * 2048);
    float p = 0.f;
#pragma unroll
    for (int c = 0; c < 8; c++) {
      float4 wv = wr[c * 64 + lane];
      p += xv[c].x * wv.x + xv[c].y * wv.y + xv[c].z * wv.z + xv[c].w * wv.w;
    }
#pragma unroll
    for (int off = 32; off; off >>= 1) p += __shfl_xor(p, off);
    lg[e] = p;
  }
  int i1 = 0;
#pragma unroll
  for (int e = 1; e < 8; e++) if (lg[e] > lg[i1]) i1 = e;
  int i2 = (i1 == 0) ? 1 : 0;
#pragma unroll
  for (int e = 0; e < 8; e++) { if (e == i1) continue; if (lg[e] > lg[i2]) i2 = e; }
  float e2 = expf(lg[i2] - lg[i1]);
  float den = 1.f + e2;
  if (lane < 8) wout[(size_t)tok * 8 + lane] =
      (lane == i1) ? (1.f / den) : ((lane == i2) ? (e2 / den) : 0.f);
}

// ---------- LoRA-down GEMM (64x128 tile, 128 blocks) ----------
__global__ __launch_bounds__(256) void k_gemm_lora(const unsigned short* __restrict__ xb,
                                                   const unsigned short* __restrict__ Ab,
                                                   const float* __restrict__ wrt,
                                                   unsigned short* __restrict__ tmat) {
  __shared__ unsigned short lsA[64 * 64];
  __shared__ unsigned short lsB[128 * 64];
  const int w = threadIdx.x >> 6, lane = threadIdx.x & 63;
  const int mBase = blockIdx.y * 64;
  const int wr = (w >> 1) * 32, wc = (w & 1) * 64;
  f32x4 z = {0.f, 0.f, 0.f, 0.f};
  f32x4 acc[2][4];
#pragma unroll
  for (int i = 0; i < 2; i++)
#pragma unroll
    for (int j = 0; j < 4; j++) acc[i][j] = z;

  for (int s = 0; s < 32; ++s) {
    int k0 = s * 64;
#pragma unroll
    for (int q = 0; q < 2; ++q) {            // A: 64 rows = 8 rowblks
      int rb = w * 2 + q;
      int r  = rb * 8 + (lane >> 3);
      int cg = (lane & 7) ^ (r & 7);
      g2lds16(xb + (size_t)(mBase + r) * 2048 + k0 + cg * 8, (char*)lsA + rb * 1024);
    }
#pragma unroll
    for (int q = 0; q < 4; ++q) {            // B: 128 rows = 16 rowblks
      int rb = w * 4 + q;
      int r  = rb * 8 + (lane >> 3);
      int cg = (lane & 7) ^ (r & 7);
      g2lds16(Ab + (size_t)r * 2048 + k0 + cg * 8, (char*)lsB + rb * 1024);
    }
    __syncthreads();
#pragma unroll
    for (int kk = 0; kk < 2; ++kk) {
      bf16x8 af[2], bv[4];
#pragma unroll
      for (int i = 0; i < 2; ++i) {
        int r = wr + i * 16 + (lane & 15);
        int c = (kk * 4 + (lane >> 4)) ^ (r & 7);
        af[i] = *(const bf16x8*)((const char*)lsA + r * 128 + c * 16);
      }
#pragma unroll
      for (int j = 0; j < 4; ++j) {
        int r = wc + j * 16 + (lane & 15);
        int c = (kk * 4 + (lane >> 4)) ^ (r & 7);
        bv[j] = *(const bf16x8*)((const char*)lsB + r * 128 + c * 16);
      }
#pragma unroll
      for (int i = 0; i < 2; ++i)
#pragma unroll
        for (int j = 0; j < 4; ++j)
          acc[i][j] = __builtin_amdgcn_mfma_f32_16x16x32_bf16(af[i], bv[j], acc[i][j], 0, 0, 0);
    }
    __syncthreads();
  }
#pragma unroll
  for (int j = 0; j < 4; ++j) {
    int jj = wc + j * 16 + (lane & 15);
    int e  = jj >> 4;
#pragma unroll
    for (int i = 0; i < 2; ++i) {
      int m0 = mBase + wr + i * 16 + (lane >> 4) * 4;
#pragma unroll
      for (int q = 0; q < 4; ++q) {
        int m = m0 + q;
        tmat[(size_t)m * 128 + jj] = f2bf(acc[i][j][q] * wrt[(size_t)m * 8 + e]);
      }
    }
  }
}

// ---------- main GEMM: 256x256 tile, BK=32, 4-buf LDS ring, counted vmcnt ----------
// out = xb.Wb^T (K=2048) ++ tmat.Bb^T (K=128) + bias.  68 K-tiles of 32.
__global__ __launch_bounds__(512, 2) void k_gemm_main(const unsigned short* __restrict__ xb,
                                                      const unsigned short* __restrict__ Wb,
                                                      const unsigned short* __restrict__ tm,
                                                      const unsigned short* __restrict__ Bb,
                                                      const float* __restrict__ bias,
                                                      float* __restrict__ out) {
  __shared__ unsigned short lds[65536];          // 128 KiB: A bufs [0,64KB), B bufs [64KB,128KB)
  const int tid = threadIdx.x, wid = tid >> 6, lane = tid & 63;
  const int wm = wid >> 2, wn = wid & 3;         // 2 x 4 waves; wave tile 128 x 64
  const int bid = blockIdx.x;
  const int s = (bid & 7) * 32 + (bid >> 3);     // XCD swizzle (256 = 8*32, bijective)
  const int mBase = (s >> 3) * 256;
  const int nBase = (s & 7) * 256;
  char* ldsc = (char*)lds;

  // staging geometry: per wave 2 ops x 1KB per matrix per tile (tile = 256 rows x 64B)
  int rS[2], cS[2];
#pragma unroll
  for (int o = 0; o < 2; ++o) {
    int r  = (wid * 2 + o) * 16 + (lane >> 2);   // row 0..255
    int cb = (lane & 3) * 16;                    // col-byte 0..48
    rS[o] = r;
    cS[o] = (cb ^ (((r >> 1) & 3) << 4)) >> 1;   // pre-swizzled source col (elems)
  }

  auto stage = [&](int t) {
    if (t >= 68) return;
    int buf = t & 3;
    const unsigned short *pa, *pb; int ld, k0;
    if (t < 64) { pa = xb; pb = Wb; ld = 2048; k0 = t * 32; }
    else        { pa = tm; pb = Bb; ld = 128;  k0 = (t - 64) * 32; }
#pragma unroll
    for (int o = 0; o < 2; ++o) {
      g2lds16(pa + (size_t)(mBase + rS[o]) * ld + k0 + cS[o],
              ldsc + buf * 16384 + (wid * 2 + o) * 1024);
      g2lds16(pb + (size_t)(nBase + rS[o]) * ld + k0 + cS[o],
              ldsc + 65536 + buf * 16384 + (wid * 2 + o) * 1024);
    }
  };

  // fragment read bases (bytes within one buf); same XOR swizzle as the source
  const int rl = lane & 15, kq = lane >> 4;
  const int swz  = ((rl >> 1) & 3) << 4;
  const int preA = (wm * 128 + rl) * 64 + ((kq * 16) ^ swz);
  const int preB = (wn * 64 + rl) * 64 + ((kq * 16) ^ swz);

  f32x4 z = {0.f, 0.f, 0.f, 0.f};
  f32x4 acc[8][4];
#pragma unroll
  for (int i = 0; i < 8; ++i)
#pragma unroll
    for (int j = 0; j < 4; ++j) acc[i][j] = z;

  stage(0); stage(1); stage(2);                  // 12 ops/wave in flight

  for (int t = 0; t < 68; ++t) {
    int rem = 67 - t;
    __builtin_amdgcn_sched_barrier(0);
    // tile t landed when <= (tiles t+1,t+2)*4 = 8 of our ops remain outstanding
    if (rem >= 2)      asm volatile("s_waitcnt vmcnt(8)" ::: "memory");
    else if (rem == 1) asm volatile("s_waitcnt vmcnt(4)" ::: "memory");
    else               asm volatile("s_waitcnt vmcnt(0)" ::: "memory");
    __builtin_amdgcn_s_barrier();
    __builtin_amdgcn_sched_barrier(0);
    stage(t + 3);                                // writes buf (t-1)&3: all readers passed barrier

    const char* bufA = ldsc + (t & 3) * 16384;
    const char* bufB = ldsc + 65536 + (t & 3) * 16384;
    bf16x8 bv[4], af[4], ag[4];
#pragma unroll
    for (int j = 0; j < 4; ++j) bv[j] = *(const bf16x8*)(bufB + preB + j * 1024);
#pragma unroll
    for (int i = 0; i < 4; ++i) af[i] = *(const bf16x8*)(bufA + preA + i * 1024);
    __builtin_amdgcn_s_setprio(1);
#pragma unroll
    for (int i = 0; i < 4; ++i)
#pragma unroll
      for (int j = 0; j < 4; ++j)
        acc[i][j] = __builtin_amdgcn_mfma_f32_16x16x32_bf16(af[i], bv[j], acc[i][j], 0, 0, 0);
    __builtin_amdgcn_s_setprio(0);
#pragma unroll
    for (int i = 0; i < 4; ++i) ag[i] = *(const bf16x8*)(bufA + preA + (4 + i) * 1024);
    __builtin_amdgcn_s_setprio(1);
#pragma unroll
    for (int i = 0; i < 4; ++i)
#pragma unroll
      for (int j = 0; j < 4; ++j)
        acc[4 + i][j] = __builtin_amdgcn_mfma_f32_16x16x32_bf16(ag[i], bv[j], acc[4 + i][j], 0, 0, 0);
    __builtin_amdgcn_s_setprio(0);
  }

#pragma unroll
  for (int j = 0; j < 4; ++j) {
    int o = nBase + wn * 64 + j * 16 + rl;
    float bb = bias[o];
#pragma unroll
    for (int i = 0; i < 8; ++i) {
      int m0 = mBase + wm * 128 + i * 16 + kq * 4;
#pragma unroll
      for (int q = 0; q < 4; ++q)
        out[(size_t)(m0 + q) * 2048 + o] = acc[i][j][q] + bb;
    }
  }
}

extern "C" void kernel_launch(void* const* d_in, const int* in_sizes, int n_in,
                              void* d_out, int out_size, void* d_ws, size_t ws_size,
                              hipStream_t stream) {
  const float* x    = (const float*)d_in[0];   // (4,2048,2048)
  const float* W    = (const float*)d_in[1];   // (2048,2048)
  const float* bias = (const float*)d_in[2];   // (2048)
  const float* Wr   = (const float*)d_in[3];   // (8,2048)
  const float* A    = (const float*)d_in[4];   // (8,2048,16)
  const float* Bexp = (const float*)d_in[5];   // (8,16,2048)
  float* out = (float*)d_out;

  char* ws = (char*)d_ws;
  unsigned short* xb = (unsigned short*)(ws);                 // 33,554,432 B
  unsigned short* Wb = (unsigned short*)(ws + 33554432);      //  8,388,608 B
  unsigned short* Ab = (unsigned short*)(ws + 41943040);      //    524,288 B
  unsigned short* Bb = (unsigned short*)(ws + 42467328);      //    524,288 B
  unsigned short* tm = (unsigned short*)(ws + 42991616);      //  2,097,152 B
  float*          wr = (float*)(ws + 45088768);               //    262,144 B

  (void)in_sizes; (void)n_in; (void)out_size; (void)ws_size;

  k_prep       <<<dim3(4096), 256, 0, stream>>>(W, A, Bexp, Wb, Ab, Bb);
  k_router_cast<<<dim3(2048), 256, 0, stream>>>(x, Wr, xb, wr);
  k_gemm_lora  <<<dim3(1, 128), 256, 0, stream>>>(xb, Ab, wr, tm);
  k_gemm_main  <<<dim3(256), 512, 0, stream>>>(xb, Wb, tm, Bb, bias, out);
}